// Round 5
// baseline (69.629 us; speedup 1.0000x reference)
//
#include <hip/hip_runtime.h>
#include <hip/hip_fp16.h>
#include <math.h>

#define N_IMG 512
#define N_ANGLES 25
#define N_DET 512
#define DET_SPACING 3.0f
#define SRC_DIST 512.0f
#define DET_DIST 512.0f
#define N_SAMPLES 1024
#define PAD 8
#define QW 528            // padded grid side: r,c in [-8, 519]
#define NQ (QW * QW)      // quads per copy
#define NGC4 132          // column groups of 4 (QW/4) for 2x4 blocking
#define NGC2 264          // column groups of 2 (QW/2) for 4x2 blocking

// ---------------------------------------------------------------------------
// ws: TWO 2.23 MB zero-padded FP16 QUAD arrays (4.46 MB total), identical
// values, different 64B-line blocking:
//   copy A: 2(rows)x4(cols) quads/line  -> new-line rate |dr|/2 + |dc|/4
//   copy B: 4(rows)x2(cols) quads/line  -> new-line rate |dr|/4 + |dc|/2
// Each RAY picks the copy matching its dominant direction (wave-uniform
// branch) -> expected unique-lines/sample drops ~19%.
//
// Model (R0/R2/R3 A/B-calibrated): fanbeam cost ~ 25 us per (line/sample);
// layout values 0.60 / 0.57 / 0.50 reproduced all three measured deltas.
// Occupancy is NOT the limiter (R4: 12800 1-wave blocks was -1.5 us WORSE);
// geometry reverted to the measured-best R3 config (3200 x 256).
// Numerics bit-identical to R3 (same fp16 corners, same fma order; only
// addresses differ) -> absmax stays exactly 0.25.
// ---------------------------------------------------------------------------

__device__ __forceinline__ int qidxA(int R, int C) {   // 2x4 blocking
    return (((R >> 1) * NGC4 + (C >> 2)) << 3) + ((R & 1) << 2) + (C & 3);
}
__device__ __forceinline__ int qidxB(int R, int C) {   // 4x2 blocking
    return (((R >> 2) * NGC2 + (C >> 1)) << 3) + ((R & 3) << 1) + (C & 1);
}

__device__ __forceinline__ float img_at(const float* __restrict__ img, int r, int c) {
    return ((unsigned)r < N_IMG && (unsigned)c < N_IMG) ? img[(r << 9) + c] : 0.0f;
}

__global__ __launch_bounds__(256) void build_quads16(const float* __restrict__ img,
                                                     uint2* __restrict__ quad) {
    int idx = blockIdx.x * 256 + (int)threadIdx.x;
    if (idx >= NQ) return;
    int R = idx / QW, C = idx - R * QW;
    int r = R - PAD, c = C - PAD;
    __half2 tp = __floats2half2_rn(img_at(img, r,     c), img_at(img, r,     c + 1));
    __half2 bt = __floats2half2_rn(img_at(img, r + 1, c), img_at(img, r + 1, c + 1));
    uint2 q;
    q.x = *reinterpret_cast<unsigned int*>(&tp);
    q.y = *reinterpret_cast<unsigned int*>(&bt);
    quad[qidxA(R, C)] = q;          // copy A (2x4)
    quad[NQ + qidxB(R, C)] = q;     // copy B (4x2)
}

// Clip [tlo,thi] to { t : lo <= v0 + t*dv <= hi }.
__device__ __forceinline__ void slab(float v0, float dv, float lo, float hi,
                                     float& tlo, float& thi) {
    if (fabsf(dv) < 1e-8f) {
        if (v0 < lo || v0 > hi) { tlo = 1.0f; thi = 0.0f; }
    } else {
        float inv = 1.0f / dv;
        float ta = (lo - v0) * inv;
        float tb = (hi - v0) * inv;
        tlo = fmaxf(tlo, fminf(ta, tb));
        thi = fminf(thi, fmaxf(ta, tb));
    }
}

__device__ __forceinline__ float bil16(uint2 q, float fc, float fr) {
    float2 top = __half22float2(*reinterpret_cast<__half2*>(&q.x));
    float2 bot = __half22float2(*reinterpret_cast<__half2*>(&q.y));
    float tv = fmaf(fc, top.y - top.x, top.x);
    float bv = fmaf(fc, bot.y - bot.x, bot.x);
    return fmaf(fr, bv - tv, tv);
}

// Sampling loop over the in-window samples; layout chosen at compile time.
template <bool USE_B>
__device__ __forceinline__ float sample_sum(const uint2* __restrict__ quad,
                                            int i_lo, int i_hi, int lane,
                                            float dx, float drow,
                                            float col0p, float row0p, float inv_n) {
    float acc = 0.0f;
    int n = i_hi - i_lo + 1;                       // wave-uniform
    int k = 0;
    // 4-deep batches: 4 independent dwordx2 gathers in flight; padded coords
    // are always >= ~5 within the window -> trunc == floor, no clamps.
    for (; k + 256 <= n; k += 256) {
        float f0 = (float)(i_lo + k + lane);       // exact in fp32
        float acc4 = 0.0f;
        #pragma unroll
        for (int j = 0; j < 4; ++j) {
            float ts  = (f0 + (64.0f * j + 0.5f)) * inv_n;
            float col = fmaf(ts, dx,   col0p);
            float row = fmaf(ts, drow, row0p);
            float cf = floorf(col), rf = floorf(row);
            float fc = col - cf,    fr = row - rf;
            int R = (int)rf, C = (int)cf;
            uint2 q = quad[USE_B ? qidxB(R, C) : qidxA(R, C)];
            acc4 += bil16(q, fc, fr);
        }
        acc += acc4;
    }
    // Tail (< 4 strides): plain loop, still clamp-free.
    #pragma unroll 2
    for (int i = i_lo + k + lane; i <= i_hi; i += 64) {
        float ts  = ((float)i + 0.5f) * inv_n;
        float col = fmaf(ts, dx,   col0p);
        float row = fmaf(ts, drow, row0p);
        float cf = floorf(col), rf = floorf(row);
        float fc = col - cf,    fr = row - rf;
        int R = (int)rf, C = (int)cf;
        uint2 q = quad[USE_B ? qidxB(R, C) : qidxA(R, C)];
        acc += bil16(q, fc, fr);
    }
    return acc;
}

// One wave per ray (R3 geometry: 3200 blocks x 256 thr); per-ray layout pick.
__global__ __launch_bounds__(256) void fanbeam_kernel(const uint2* __restrict__ quad,
                                                      float* __restrict__ out) {
    const int gid  = blockIdx.x * 256 + (int)threadIdx.x;
    const int ray  = gid >> 6;
    const int lane = (int)threadIdx.x & 63;
    if (ray >= N_ANGLES * N_DET) return;

    const int a = ray >> 9;
    const int d = ray & 511;

    float beta = (2.0f * (float)a / 25.0f) * 3.14159265358979323846f;
    float c, s;
    __sincosf(beta, &s, &c);
    float t = ((float)d - (N_DET - 1) * 0.5f) * DET_SPACING;
    float srcx = -SRC_DIST * s;
    float srcy =  SRC_DIST * c;
    float dx = (t * c + DET_DIST * s) - srcx;
    float dy = (t * s - DET_DIST * c) - srcy;
    float seg = sqrtf(dx * dx + dy * dy);

    const float half = (N_IMG - 1) * 0.5f;
    const float col0 = srcx + half;            // unpadded (for clipping)
    const float row0 = half - srcy;
    const float drow = -dy;
    const float col0p = col0 + (float)PAD;     // padded-coordinate origins
    const float row0p = row0 + (float)PAD;
    const float inv_n = 1.0f / N_SAMPLES;

    float tA = 0.0f, tB = 1.0f;
    slab(col0, dx,   -1.01f, 512.01f, tA, tB);
    slab(row0, drow, -1.01f, 512.01f, tA, tB);

    float acc = 0.0f;
    if (tA <= tB) {
        int i_lo = max(0,             (int)floorf(tA * N_SAMPLES - 0.5f) - 1);
        int i_hi = min(N_SAMPLES - 1, (int)ceilf (tB * N_SAMPLES - 0.5f) + 1);
        // Wave-uniform layout pick: col-ish rays (row advances fastest) use
        // the 4-row-blocked copy B; row-ish rays use the 4-col-blocked copy A.
        if (fabsf(drow) > fabsf(dx))
            acc = sample_sum<true >(quad + NQ, i_lo, i_hi, lane, dx, drow, col0p, row0p, inv_n);
        else
            acc = sample_sum<false>(quad,      i_lo, i_hi, lane, dx, drow, col0p, row0p, inv_n);
    }

    #pragma unroll
    for (int off = 32; off > 0; off >>= 1)
        acc += __shfl_down(acc, off, 64);

    if (lane == 0) out[ray] = acc * (seg * inv_n);
}

extern "C" void kernel_launch(void* const* d_in, const int* in_sizes, int n_in,
                              void* d_out, int out_size, void* d_ws, size_t ws_size,
                              hipStream_t stream) {
    const float* img = (const float*)d_in[0];
    float* out = (float*)d_out;
    uint2* quad = (uint2*)d_ws;                    // 2 copies x 2.23 MB = 4.46 MB

    build_quads16<<<(NQ + 255) / 256, 256, 0, stream>>>(img, quad);

    const int n_rays = N_ANGLES * N_DET;           // 12800 rays, 1 wave each
    fanbeam_kernel<<<n_rays * 64 / 256, 256, 0, stream>>>(quad, out);
}